// Round 6
// baseline (147.636 us; speedup 1.0000x reference)
//
#include <hip/hip_runtime.h>

#define HH 1024
#define WW 1024
#define NB 16
#define TR 8                        // output rows per block
#define SR (TR + 4)                 // staged rows: y0-2 .. y0+TR+1
#define NBLK (NB * (HH / TR))       // 2048 blocks
#define NELEM ((long long)NB * HH * WW)

// Read LDS row (row) into 8 NAMED scalars W0..W7 covering cols [c0-2..c0+5].
// Named scalars (no arrays) -> SROA cannot fail -> no scratch (R2/R4 lesson).
// f2/f4/f2 pieces at 16B lane stride = 2 lanes/bank = conflict-free (m136).
// Edge zeroing identical to the proven R0 lds_win (absmax 0.0 preserved).
#define LWIN(row, W) \
    const float* W##_p = S + (row) * WW; \
    const float2 W##_L = *(const float2*)(W##_p + (ledge ? c0 : c0 - 2)); \
    const float4 W##_M = *(const float4*)(W##_p + c0); \
    const float2 W##_R = *(const float2*)(W##_p + (redge ? c0 : c0 + 4)); \
    const float W##0 = ledge ? 0.f : W##_L.x; \
    const float W##1 = ledge ? 0.f : W##_L.y; \
    const float W##2 = W##_M.x; \
    const float W##3 = W##_M.y; \
    const float W##4 = W##_M.z; \
    const float W##5 = W##_M.w; \
    const float W##6 = redge ? 0.f : W##_R.x; \
    const float W##7 = redge ? 0.f : W##_R.y;

// One output element. Same per-element formula; max/min chain reassociated
// (fp max/min are exactly associative/commutative -> values bit-identical).
// log1p(-c) == log(1-c) exactly in fp32 for c in [0.5,1) (Sterbenz).
#define COL1(v3l, v2c, v3r, u3l, u2c, u3r, cc, tt) { \
    const float c   = cc; \
    const float mx  = fmaxf(fmaxf(v3l, v2c), v3r); \
    const float mn  = fminf(fminf(u3l, u2c), u3r); \
    const float w   = fmaxf(mx - c, c - mn); \
    const float lp  = fmaxf(__logf(c), -100.f); \
    const float l1p = fmaxf(__logf(1.f - c), -100.f); \
    const float th  = (c >= 0.5f) ? c : 0.f; \
    sum += w * th - l1p - (tt) * (lp - l1p); }

// One output row k from register windows A (y-2), B (y), C (y+2).
// Separable 8-neighborhood: V3[p]=max(A,B,C) shared by cols j-2/j+2 (B's
// side values ARE neighbors), V2[p]=max(A,C) for the center column (B center
// excluded). Max ops per 4 outputs: 28 -> 16 (same for min).
#define ROWC(A, B, C, k) { \
    const float4 _t = *(const float4*)(tbase + (k) * WW + c0); \
    const float x0 = fmaxf(fmaxf(A##0, B##0), C##0); \
    const float x1 = fmaxf(fmaxf(A##1, B##1), C##1); \
    const float x2 = fmaxf(fmaxf(A##2, B##2), C##2); \
    const float x3 = fmaxf(fmaxf(A##3, B##3), C##3); \
    const float x4 = fmaxf(fmaxf(A##4, B##4), C##4); \
    const float x5 = fmaxf(fmaxf(A##5, B##5), C##5); \
    const float x6 = fmaxf(fmaxf(A##6, B##6), C##6); \
    const float x7 = fmaxf(fmaxf(A##7, B##7), C##7); \
    const float n0 = fminf(fminf(A##0, B##0), C##0); \
    const float n1 = fminf(fminf(A##1, B##1), C##1); \
    const float n2 = fminf(fminf(A##2, B##2), C##2); \
    const float n3 = fminf(fminf(A##3, B##3), C##3); \
    const float n4 = fminf(fminf(A##4, B##4), C##4); \
    const float n5 = fminf(fminf(A##5, B##5), C##5); \
    const float n6 = fminf(fminf(A##6, B##6), C##6); \
    const float n7 = fminf(fminf(A##7, B##7), C##7); \
    const float y2 = fmaxf(A##2, C##2); \
    const float y3 = fmaxf(A##3, C##3); \
    const float y4 = fmaxf(A##4, C##4); \
    const float y5 = fmaxf(A##5, C##5); \
    const float m2 = fminf(A##2, C##2); \
    const float m3 = fminf(A##3, C##3); \
    const float m4 = fminf(A##4, C##4); \
    const float m5 = fminf(A##5, C##5); \
    COL1(x0, y2, x4, n0, m2, n4, B##2, _t.x) \
    COL1(x1, y3, x5, n1, m3, n5, B##3, _t.y) \
    COL1(x2, y4, x6, n2, m4, n6, B##4, _t.z) \
    COL1(x3, y5, x7, n3, m5, n7, B##5, _t.w) }

// R0 structure (12-row LDS stage -> barrier -> pure-LDS compute) with the
// compute phase rebuilt: each LDS row is read ONCE into a named register
// window (36 ds_reads/thread, was 72) and rolls through the 8 k-iterations
// SSA-style; max/min separably factored (-6 VALU/elem, exact).
// (256,2): allocator may use up to 256 VGPR; occupancy stays LDS-bound at
// 3 blocks/CU either way (R5 proved 12 vs 24 waves/CU is perf-neutral).
__global__ __launch_bounds__(256, 2) void closs_main(const float* __restrict__ yt,
                                                     const float* __restrict__ yp,
                                                     float* __restrict__ partial) {
    __shared__ float S[SR * WW];        // 48 KB -> 3 blocks/CU resident

    const int bid  = blockIdx.x;
    const int img  = bid >> 7;          // 128 tiles per image
    const int tile = bid & 127;
    const int y0   = tile * TR;
    const int tid  = threadIdx.x;
    const int c0   = tid << 2;          // 4 columns per thread

    const float* __restrict__ ybase = yp + (long long)img * (HH * WW);
    const float* __restrict__ tbase = yt + ((long long)img * HH + y0) * WW;

    // Stage SR=12 rows as pure aligned float4 streams (proven R0 pattern).
    // Rows outside [0,HH) zero-filled == reference zero padding. Block-
    // uniform branch, no divergence.
#pragma unroll
    for (int i = 0; i < SR; ++i) {
        const int gy = y0 - 2 + i;
        float4 v = make_float4(0.f, 0.f, 0.f, 0.f);
        if (gy >= 0 && gy < HH)
            v = *(const float4*)(ybase + gy * WW + c0);
        *(float4*)&S[i * WW + c0] = v;
    }
    __syncthreads();

    const bool ledge = (tid == 0);
    const bool redge = (tid == 255);

    float sum = 0.f;

    // Preload windows for LDS rows 0..4, then roll: row k uses windows
    // k (y-2), k+2 (y), k+4 (y+2); next row's window loads ahead of use.
    LWIN(0, W0)
    LWIN(1, W1)
    LWIN(2, W2)
    LWIN(3, W3)
    LWIN(4, W4)
    LWIN(5, W5)   ROWC(W0, W2, W4, 0)
    LWIN(6, W6)   ROWC(W1, W3, W5, 1)
    LWIN(7, W7)   ROWC(W2, W4, W6, 2)
    LWIN(8, W8)   ROWC(W3, W5, W7, 3)
    LWIN(9, W9)   ROWC(W4, W6, W8, 4)
    LWIN(10, W10) ROWC(W5, W7, W9, 5)
    LWIN(11, W11) ROWC(W6, W8, W10, 6)
                  ROWC(W7, W9, W11, 7)

    // Block reduction -> one partial write (no atomics: R4 proved 16K
    // same-address atomicAdds serialize to ~215 us).
    for (int o = 32; o > 0; o >>= 1) sum += __shfl_down(sum, o);
    __shared__ float wsum[4];
    if ((tid & 63) == 0) wsum[tid >> 6] = sum;
    __syncthreads();
    if (tid == 0) partial[bid] = wsum[0] + wsum[1] + wsum[2] + wsum[3];
}

// Final reduction over 2048 partials in one 1024-thread block.
__global__ __launch_bounds__(1024) void closs_reduce(const float* __restrict__ partial,
                                                     float* __restrict__ out) {
    const float2* p2 = (const float2*)partial;    // 1024 float2s
    float2 v = p2[threadIdx.x];
    float s = v.x + v.y;
    for (int o = 32; o > 0; o >>= 1) s += __shfl_down(s, o);
    __shared__ float wsum[16];
    if ((threadIdx.x & 63) == 0) wsum[threadIdx.x >> 6] = s;
    __syncthreads();
    if (threadIdx.x == 0) {
        float t = 0.f;
#pragma unroll
        for (int i = 0; i < 16; ++i) t += wsum[i];
        out[0] = t * (1.0f / (float)NELEM);
    }
}

extern "C" void kernel_launch(void* const* d_in, const int* in_sizes, int n_in,
                              void* d_out, int out_size, void* d_ws, size_t ws_size,
                              hipStream_t stream) {
    const float* y_true = (const float*)d_in[0];
    const float* y_pred = (const float*)d_in[1];
    float* out = (float*)d_out;
    float* partial = (float*)d_ws;   // NBLK*4 = 8 KB scratch

    closs_main<<<NBLK, 256, 0, stream>>>(y_true, y_pred, partial);
    closs_reduce<<<1, 1024, 0, stream>>>(partial, out);
}

// Round 8
// 146.002 us; speedup vs baseline: 1.0112x; 1.0112x over previous
//
#include <hip/hip_runtime.h>

#define HH 1024
#define WW 1024
#define NB 16
#define TRB 16                      // output rows per block (2 phases x 8)
#define SRB 20                      // staged rows: y0-2 .. y0+17
#define NBLK (NB * (HH / TRB))      // 1024 blocks
#define NELEM ((long long)NB * HH * WW)

// Read an 8-float stencil window [c0-2 .. c0+5] from an LDS row.
// Lane stride is 16 B -> 2 lanes/bank on all pieces = conflict-free (m136).
__device__ __forceinline__ void lds_win(const float* __restrict__ S, int row,
                                        int c0, bool ledge, bool redge, float w[8]) {
    const float* p = S + row * WW;
    float2 L = *(const float2*)(p + (ledge ? c0 : c0 - 2));
    float4 M = *(const float4*)(p + c0);
    float2 R = *(const float2*)(p + (redge ? c0 : c0 + 4));
    if (ledge) { L.x = 0.f; L.y = 0.f; }
    if (redge) { R.x = 0.f; R.y = 0.f; }
    w[0]=L.x; w[1]=L.y; w[2]=M.x; w[3]=M.y; w[4]=M.z; w[5]=M.w; w[6]=R.x; w[7]=R.y;
}

// Per-output-row math: identical op ordering to the proven 46 us kernel.
__device__ __forceinline__ void row4(const float A[8], const float B[8],
                                     const float C[8], const float4 t4,
                                     float& sum) {
    const float tt[4] = {t4.x, t4.y, t4.z, t4.w};
#pragma unroll
    for (int j = 0; j < 4; ++j) {
        const float c = B[j + 2];
        // max|c-nb| = max(max(nb)-c, c-min(nb)); folds to v_max3/v_min3.
        const float mxA = fmaxf(fmaxf(A[j], A[j + 2]), A[j + 4]);
        const float mxB = fmaxf(B[j], B[j + 4]);
        const float mxC = fmaxf(fmaxf(C[j], C[j + 2]), C[j + 4]);
        const float mx  = fmaxf(fmaxf(mxA, mxB), mxC);
        const float mnA = fminf(fminf(A[j], A[j + 2]), A[j + 4]);
        const float mnB = fminf(B[j], B[j + 4]);
        const float mnC = fminf(fminf(C[j], C[j + 2]), C[j + 4]);
        const float mn  = fminf(fminf(mnA, mnB), mnC);
        const float w   = fmaxf(mx - c, c - mn);

        // log1p(-c) == log(1-c) exactly in fp32 for c in [0.5,1) (Sterbenz);
        // -100 clamp covers c -> 1 / c == 0.
        const float lp  = fmaxf(__logf(c), -100.f);
        const float l1p = fmaxf(__logf(1.f - c), -100.f);
        const float th  = (c >= 0.5f) ? c : 0.f;
        sum += w * th - l1p - tt[j] * (lp - l1p);
    }
}

// 16-row tile, two 8-row phases, software-pipelined staging (T14 pattern):
// phase-1's 8 staging rows are loaded to registers BEFORE phase-0 compute
// (HBM/LLC latency hides under ~4k cycles of math) and ds-written after it.
// Halo overhead drops to 20/16 = 1.25x (was 12/8 = 1.5x): logical y_pred
// traffic 96 -> 80 MB. LDS = 20 rows * 4 KB = 81920 B exactly -> 2 blocks/CU
// (16 waves/CU); reduction reuses S row 0 to avoid tipping over 80 KB.
__global__ __launch_bounds__(512, 4) void closs_main(const float* __restrict__ yt,
                                                     const float* __restrict__ yp,
                                                     float* __restrict__ partial) {
    __shared__ float S[SRB * WW];       // 80 KB exactly

    const int bid   = blockIdx.x;
    const int img   = bid >> 6;         // 64 tiles per image
    const int tile  = bid & 63;
    const int y0    = tile << 4;        // * TRB
    const int tid   = threadIdx.x;
    const int lane  = tid & 255;        // column group
    const int rhalf = tid >> 8;         // row-half within each phase
    const int c0    = lane << 2;        // 4 columns per thread

    const float* __restrict__ ybase = yp + (long long)img * (HH * WW);
    const float* __restrict__ tbase = yt + ((long long)img * HH + y0) * WW;

    const bool ledge = (lane == 0);
    const bool redge = (lane == 255);

    // ---- stage0: LDS rows 0..11 (global rows y0-2 .. y0+9), 6 per half.
    // Rows outside [0,HH) zero-filled == reference zero padding (uniform).
#pragma unroll
    for (int ii = 0; ii < 6; ++ii) {
        const int r  = (ii << 1) + rhalf;
        const int gy = y0 - 2 + r;
        float4 v = make_float4(0.f, 0.f, 0.f, 0.f);
        if (gy >= 0 && gy < HH)
            v = *(const float4*)(ybase + gy * WW + c0);
        *(float4*)&S[r * WW + c0] = v;
    }
    __syncthreads();

    const int kb0 = rhalf << 2;         // phase-0 rows: 0-3 or 4-7

    // Prefetch phase-0 y_true (oldest loads; their use never drains P/T1).
    float4 T0[4];
#pragma unroll
    for (int q = 0; q < 4; ++q)
        T0[q] = *(const float4*)(tbase + (kb0 + q) * WW + c0);

    // Issue phase-1 staging loads (LDS rows 12..19 = global y0+10..y0+17)
    // into registers NOW; written to LDS after phase-0 compute.
    float4 P[4];
#pragma unroll
    for (int ii = 0; ii < 4; ++ii) {
        const int r  = 12 + (ii << 1) + rhalf;
        const int gy = y0 - 2 + r;      // >= 10, only upper bound can fail
        float4 v = make_float4(0.f, 0.f, 0.f, 0.f);
        if (gy < HH)
            v = *(const float4*)(ybase + gy * WW + c0);
        P[ii] = v;
    }

    // ---- phase-0 compute: output rows kb0..kb0+3, LDS idx k, k+2, k+4 <= 11.
    float sum = 0.f;
#pragma unroll
    for (int q = 0; q < 4; ++q) {
        const int k = kb0 + q;
        float A[8], B[8], C[8];
        lds_win(S, k,     c0, ledge, redge, A);
        lds_win(S, k + 2, c0, ledge, redge, B);
        lds_win(S, k + 4, c0, ledge, redge, C);
        row4(A, B, C, T0[q], sum);
    }

    // Prefetch phase-1 y_true before the P-writes so the vmcnt wait for P
    // (older) leaves these (younger) in flight across the barrier.
    const int kb1 = 8 + kb0;            // phase-1 rows: 8-11 or 12-15
    float4 T1[4];
#pragma unroll
    for (int q = 0; q < 4; ++q)
        T1[q] = *(const float4*)(tbase + (kb1 + q) * WW + c0);

    // ---- stage1 write: rows 12..19 (loads have had phase-0 to land).
#pragma unroll
    for (int ii = 0; ii < 4; ++ii) {
        const int r = 12 + (ii << 1) + rhalf;
        *(float4*)&S[r * WW + c0] = P[ii];
    }
    __syncthreads();

    // ---- phase-1 compute: output rows kb1..kb1+3, LDS idx k..k+4 in [8,19].
#pragma unroll
    for (int q = 0; q < 4; ++q) {
        const int k = kb1 + q;
        float A[8], B[8], C[8];
        lds_win(S, k,     c0, ledge, redge, A);
        lds_win(S, k + 2, c0, ledge, redge, B);
        lds_win(S, k + 4, c0, ledge, redge, C);
        row4(A, B, C, T1[q], sum);
    }

    // Block reduction over 8 waves -> one partial write. Reuse S[0..7]
    // (row 0; phase-1 readers touch rows >= 8 only -> no alias, and each
    // wave writes after its own reads are done).
    for (int o = 32; o > 0; o >>= 1) sum += __shfl_down(sum, o);
    if ((tid & 63) == 0) S[tid >> 6] = sum;
    __syncthreads();
    if (tid == 0) {
        float t = 0.f;
#pragma unroll
        for (int i = 0; i < 8; ++i) t += S[i];
        partial[bid] = t;
    }
}

// Final reduction over 1024 partials in one 1024-thread block.
__global__ __launch_bounds__(1024) void closs_reduce(const float* __restrict__ partial,
                                                     float* __restrict__ out) {
    float s = partial[threadIdx.x];
    for (int o = 32; o > 0; o >>= 1) s += __shfl_down(s, o);
    __shared__ float wsum[16];
    if ((threadIdx.x & 63) == 0) wsum[threadIdx.x >> 6] = s;
    __syncthreads();
    if (threadIdx.x == 0) {
        float t = 0.f;
#pragma unroll
        for (int i = 0; i < 16; ++i) t += wsum[i];
        out[0] = t * (1.0f / (float)NELEM);
    }
}

extern "C" void kernel_launch(void* const* d_in, const int* in_sizes, int n_in,
                              void* d_out, int out_size, void* d_ws, size_t ws_size,
                              hipStream_t stream) {
    const float* y_true = (const float*)d_in[0];
    const float* y_pred = (const float*)d_in[1];
    float* out = (float*)d_out;
    float* partial = (float*)d_ws;   // NBLK*4 = 4 KB scratch

    closs_main<<<NBLK, 512, 0, stream>>>(y_true, y_pred, partial);
    closs_reduce<<<1, 1024, 0, stream>>>(partial, out);
}

// Round 9
// 143.808 us; speedup vs baseline: 1.0266x; 1.0153x over previous
//
#include <hip/hip_runtime.h>

#define HH 1024
#define WW 1024
#define NB 16
#define TR 8                        // output rows per block
#define SR (TR + 4)                 // staged rows: y0-2 .. y0+TR+1
#define NBLK (NB * (HH / TR))       // 2048 blocks
#define NELEM ((long long)NB * HH * WW)

// Read an 8-float stencil window [c0-2 .. c0+5] from an LDS row.
// Lane stride is 16 B -> 2 lanes/bank on all pieces = conflict-free (m136).
__device__ __forceinline__ void lds_win(const float* __restrict__ S, int row,
                                        int c0, bool ledge, bool redge, float w[8]) {
    const float* p = S + row * WW;
    float2 L = *(const float2*)(p + (ledge ? c0 : c0 - 2));
    float4 M = *(const float4*)(p + c0);
    float2 R = *(const float2*)(p + (redge ? c0 : c0 + 4));
    if (ledge) { L.x = 0.f; L.y = 0.f; }
    if (redge) { R.x = 0.f; R.y = 0.f; }
    w[0]=L.x; w[1]=L.y; w[2]=M.x; w[3]=M.y; w[4]=M.z; w[5]=M.w; w[6]=R.x; w[7]=R.y;
}

// Best measured configuration (R5: kernel 46.1 us, bench 145.7 us).
// 12-row LDS stage -> one barrier -> pure-LDS compute; 512 threads/block
// (3 blocks/CU x 8 waves = 24 waves/CU). Session evidence: occupancy x2
// (R5), DS/2 (R6), VALU -20% (R6), traffic -10% (R8), de-LDS (R2/R4), and
// 2-phase pipelining (R8) all fail to beat this 46 us plateau; warm-cache
// replays run at the same time with ~zero HBM traffic (on-chip floor).
__global__ __launch_bounds__(512) void closs_main(const float* __restrict__ yt,
                                                  const float* __restrict__ yp,
                                                  float* __restrict__ partial) {
    __shared__ float S[SR * WW];        // 48 KB -> 3 blocks/CU resident

    const int bid   = blockIdx.x;
    const int img   = bid >> 7;         // 128 tiles per image
    const int tile  = bid & 127;
    const int y0    = tile * TR;
    const int tid   = threadIdx.x;
    const int lane  = tid & 255;        // column group
    const int rhalf = tid >> 8;         // 0: rows 0-3, 1: rows 4-7
    const int c0    = lane << 2;        // 4 columns per thread

    const float* __restrict__ ybase = yp + (long long)img * (HH * WW);
    const float* __restrict__ tbase = yt + ((long long)img * HH + y0) * WW;

    // Stage SR=12 rows as aligned float4 streams; 6 rows per thread-half
    // (even rows by tid<256, odd rows by tid>=256 -> branch wave-uniform).
    // Rows outside [0,HH) zero-filled == reference zero padding.
#pragma unroll
    for (int ii = 0; ii < 6; ++ii) {
        const int r  = (ii << 1) + rhalf;
        const int gy = y0 - 2 + r;
        float4 v = make_float4(0.f, 0.f, 0.f, 0.f);
        if (gy >= 0 && gy < HH)
            v = *(const float4*)(ybase + gy * WW + c0);
        *(float4*)&S[r * WW + c0] = v;
    }
    __syncthreads();

    const bool ledge = (lane == 0);
    const bool redge = (lane == 255);
    const int  kb    = rhalf << 2;      // first output row of this half

    float sum = 0.f;
#pragma unroll
    for (int k2 = 0; k2 < 4; ++k2) {
        const int k = kb + k2;
        float A[8], B[8], C[8];         // LDS rows k (y-2), k+2 (y), k+4 (y+2)
        lds_win(S, k,     c0, ledge, redge, A);
        lds_win(S, k + 2, c0, ledge, redge, B);
        lds_win(S, k + 4, c0, ledge, redge, C);

        const float4 t4 = *(const float4*)(tbase + k * WW + c0);
        const float tt[4] = {t4.x, t4.y, t4.z, t4.w};

#pragma unroll
        for (int j = 0; j < 4; ++j) {
            const float c = B[j + 2];
            // max|c-nb| = max(max(nb)-c, c-min(nb)); bit-identical to the
            // |diff| chain; folds to v_max3/v_min3.
            const float mxA = fmaxf(fmaxf(A[j], A[j + 2]), A[j + 4]);
            const float mxB = fmaxf(B[j], B[j + 4]);
            const float mxC = fmaxf(fmaxf(C[j], C[j + 2]), C[j + 4]);
            const float mx  = fmaxf(fmaxf(mxA, mxB), mxC);
            const float mnA = fminf(fminf(A[j], A[j + 2]), A[j + 4]);
            const float mnB = fminf(B[j], B[j + 4]);
            const float mnC = fminf(fminf(C[j], C[j + 2]), C[j + 4]);
            const float mn  = fminf(fminf(mnA, mnB), mnC);
            const float w   = fmaxf(mx - c, c - mn);

            // log1p(-c) == log(1-c) exactly in fp32 for c in [0.5,1)
            // (Sterbenz); -100 clamp covers c -> 1 / c == 0.
            const float lp  = fmaxf(__logf(c), -100.f);
            const float l1p = fmaxf(__logf(1.f - c), -100.f);
            const float th  = (c >= 0.5f) ? c : 0.f;
            sum += w * th - l1p - tt[j] * (lp - l1p);
        }
    }

    // Block reduction over 8 waves -> one partial write (no atomics: 16K
    // same-address atomicAdds serialize to ~215 us).
    for (int o = 32; o > 0; o >>= 1) sum += __shfl_down(sum, o);
    __shared__ float wsum[8];
    if ((tid & 63) == 0) wsum[tid >> 6] = sum;
    __syncthreads();
    if (tid == 0) {
        float t = 0.f;
#pragma unroll
        for (int i = 0; i < 8; ++i) t += wsum[i];
        partial[bid] = t;
    }
}

// Final reduction over 2048 partials in one 1024-thread block.
__global__ __launch_bounds__(1024) void closs_reduce(const float* __restrict__ partial,
                                                     float* __restrict__ out) {
    const float2* p2 = (const float2*)partial;    // 1024 float2s
    float2 v = p2[threadIdx.x];
    float s = v.x + v.y;
    for (int o = 32; o > 0; o >>= 1) s += __shfl_down(s, o);
    __shared__ float wsum[16];
    if ((threadIdx.x & 63) == 0) wsum[threadIdx.x >> 6] = s;
    __syncthreads();
    if (threadIdx.x == 0) {
        float t = 0.f;
#pragma unroll
        for (int i = 0; i < 16; ++i) t += wsum[i];
        out[0] = t * (1.0f / (float)NELEM);
    }
}

extern "C" void kernel_launch(void* const* d_in, const int* in_sizes, int n_in,
                              void* d_out, int out_size, void* d_ws, size_t ws_size,
                              hipStream_t stream) {
    const float* y_true = (const float*)d_in[0];
    const float* y_pred = (const float*)d_in[1];
    float* out = (float*)d_out;
    float* partial = (float*)d_ws;   // NBLK*4 = 8 KB scratch

    closs_main<<<NBLK, 512, 0, stream>>>(y_true, y_pred, partial);
    closs_reduce<<<1, 1024, 0, stream>>>(partial, out);
}